// Round 5
// baseline (1214.393 us; speedup 1.0000x reference)
//
#include <hip/hip_runtime.h>

#define NB 4
#define NH 16
#define NS 2048
#define ND 64

typedef __attribute__((ext_vector_type(8))) short short8;
typedef __attribute__((ext_vector_type(4))) float floatx4;
typedef __attribute__((ext_vector_type(4))) int intx4;
typedef __attribute__((ext_vector_type(4))) unsigned uintx4;

__device__ __forceinline__ unsigned short f2bf(float f) {
  unsigned u = __builtin_bit_cast(unsigned, f);
  u = (u + 0x7FFFu + ((u >> 16) & 1u)) >> 16;  // RNE
  return (unsigned short)u;
}
__device__ __forceinline__ float bf2f(unsigned u16) {
  unsigned u = u16 << 16;
  return __builtin_bit_cast(float, u);
}

// ---- prep: K fp32 -> bf16, same [b,h,k,d] layout ----
__global__ __launch_bounds__(256) void prep_k_kernel(const float* __restrict__ K,
                                                     unsigned short* __restrict__ kb) {
  size_t i = ((size_t)blockIdx.x * 256 + threadIdx.x) * 4;
  floatx4 v = *(const floatx4*)(K + i);
  unsigned long long o = 0;
  o |= (unsigned long long)f2bf(v[0]);
  o |= (unsigned long long)f2bf(v[1]) << 16;
  o |= (unsigned long long)f2bf(v[2]) << 32;
  o |= (unsigned long long)f2bf(v[3]) << 48;
  *(unsigned long long*)(kb + i) = o;
}

// ---- prep: V [bh][k][d] fp32 -> VT [bh][d][k] bf16 ----
__global__ __launch_bounds__(256) void prep_vt_kernel(const float* __restrict__ V,
                                                      unsigned short* __restrict__ vt) {
  __shared__ float tile[64][65];
  int kc = blockIdx.x & 31;
  int bh = blockIdx.x >> 5;
  int k0 = kc * 64;
  const float* src = V + ((size_t)bh * NS + k0) * ND;
  int t = threadIdx.x;
  int r0 = t >> 4;
  int c = (t & 15) * 4;
  for (int rr = 0; rr < 4; ++rr) {
    int r = rr * 16 + r0;
    floatx4 v = *(const floatx4*)(src + (size_t)r * ND + c);
    tile[r][c + 0] = v[0]; tile[r][c + 1] = v[1];
    tile[r][c + 2] = v[2]; tile[r][c + 3] = v[3];
  }
  __syncthreads();
  unsigned short* dst = vt + (size_t)bh * ND * NS + k0;
  for (int i = 0; i < 16; ++i) {
    int lin = i * 256 + t;
    int d = lin >> 6, k = lin & 63;
    dst[(size_t)d * NS + k] = f2bf(tile[k][d]);
  }
}

// Common Q B-frag loader: swapped QK (mfma(K,Q)), 1/8 scale folded in (2^-3 exact).
__device__ __forceinline__ void load_q_frags(const float* __restrict__ Q, size_t bh,
                                             int q0, int lc, int lg8,
                                             short8& aq0, short8& aq1) {
  const float* qrow = Q + (bh * NS + (size_t)(q0 + lc)) * ND + lg8;
  floatx4 f0 = *(const floatx4*)(qrow);
  floatx4 f1 = *(const floatx4*)(qrow + 4);
  floatx4 f2 = *(const floatx4*)(qrow + 32);
  floatx4 f3 = *(const floatx4*)(qrow + 36);
#pragma unroll
  for (int j = 0; j < 4; ++j) {
    aq0[j] = (short)f2bf(f0[j] * 0.125f);
    aq0[4 + j] = (short)f2bf(f1[j] * 0.125f);
    aq1[j] = (short)f2bf(f2[j] * 0.125f);
    aq1[4 + j] = (short)f2bf(f3[j] * 0.125f);
  }
}

// ---- pass 1: rowsums only. No P store, tiny LDS, VGPR-lean -> 32 waves/CU ----
__global__ __launch_bounds__(512) void sum_kernel(
    const float* __restrict__ Q,
    const unsigned short* __restrict__ Kb,
    const int* __restrict__ mask,
    const float* __restrict__ bias,
    float* __restrict__ rs) {
  __shared__ float sums[8][16];

  const int bid = blockIdx.x;
  const int b = bid & 3;                // batch fastest -> bias shared via L2/L3
  const int qt = (bid >> 2) & 127;
  const int h = bid >> 9;
  const int q0 = qt * 16;

  const int tid = threadIdx.x;
  const int wave = tid >> 6;  // 0..7, k-strip [256w, 256w+256)
  const int lane = tid & 63;
  const int lg = lane >> 4;
  const int lc = lane & 15;
  const int lg4 = lg * 4;
  const int lg8 = lg * 8;
  const size_t bh = (size_t)(b * NH + h);

  short8 aq0, aq1;
  load_q_frags(Q, bh, q0, lc, lg8, aq0, aq1);

  const unsigned short* kp = Kb + bh * NS * ND + (size_t)lc * ND + lg8;
  const float* bp = bias + ((size_t)h * NS + (size_t)(q0 + lc)) * NS + lg4;
  const int* mp = mask + b * NS + lg4;
  const int ksb = wave * 256;

  float psum = 0.f;
#pragma unroll
  for (int it = 0; it < 16; ++it) {
    const int k0 = ksb + it * 16;
    short8 kA = *(const short8*)(kp + (size_t)k0 * ND);
    short8 kB = *(const short8*)(kp + (size_t)k0 * ND + 32);
    floatx4 bV = *(const floatx4*)(bp + k0);
    intx4 mV = *(const intx4*)(mp + k0);
    floatx4 c = bV;
    c = __builtin_amdgcn_mfma_f32_16x16x32_bf16(kA, aq0, c, 0, 0, 0);
    c = __builtin_amdgcn_mfma_f32_16x16x32_bf16(kB, aq1, c, 0, 0, 0);
    float p0 = mV[0] ? __expf(c[0]) : 0.f;
    float p1 = mV[1] ? __expf(c[1]) : 0.f;
    float p2 = mV[2] ? __expf(c[2]) : 0.f;
    float p3 = mV[3] ? __expf(c[3]) : 0.f;
    psum += (p0 + p1) + (p2 + p3);
  }
  // lanes {l, l^16, l^32, l^48} share q=lc
  psum += __shfl_xor(psum, 16);
  psum += __shfl_xor(psum, 32);
  if (lane < 16) sums[wave][lane] = psum;
  __syncthreads();
  if (tid < 16) {
    float t = 0.f;
#pragma unroll
    for (int w = 0; w < 8; ++w) t += sums[w][tid];
    rs[(bh << 11) + q0 + tid] = t;
  }
}

// ---- pass 2: recompute scores, scale by known 1/rowsum, write attn + PV + out ----
// No LDS-P: swapped-QK C-frag -> 2-round 4-lane shuffle transpose -> PV A-frag.
// No mid-kernel barriers; waves stream independently until the final O-reduce.
__global__ __launch_bounds__(512, 4) void attn_kernel(
    const float* __restrict__ Q,
    const unsigned short* __restrict__ Kb,
    const unsigned short* __restrict__ VT,
    const int* __restrict__ mask,
    const float* __restrict__ bias,
    const float* __restrict__ rs,
    float* __restrict__ out,
    float* __restrict__ attn) {
  __shared__ float Ored[8][16][64];  // 32 KB, used only at the end

  const int bid = blockIdx.x;
  const int b = bid & 3;
  const int qt = (bid >> 2) & 127;
  const int h = bid >> 9;
  const int q0 = qt * 16;

  const int tid = threadIdx.x;
  const int wave = tid >> 6;  // 0..7, k-strip [256w, 256w+256)
  const int lane = tid & 63;
  const int lg = lane >> 4;
  const int lc = lane & 15;
  const int lg4 = lg * 4;
  const int lg8 = lg * 8;
  const size_t bh = (size_t)(b * NH + h);

  short8 aq0, aq1;
  load_q_frags(Q, bh, q0, lc, lg8, aq0, aq1);
  const float inv = 1.f / rs[(bh << 11) + q0 + lc];  // row q0+lc

  const unsigned short* kp = Kb + bh * NS * ND + (size_t)lc * ND + lg8;
  const float* bp = bias + ((size_t)h * NS + (size_t)(q0 + lc)) * NS + lg4;
  const int* mp = mask + b * NS + lg4;
  const unsigned short* vp = VT + bh * (size_t)ND * NS + (size_t)lc * NS + lg8;
  float* arow = attn + (bh * NS + (size_t)(q0 + lc)) * NS + lg8;
  const int ksb = wave * 256;

  floatx4 o0 = {0.f, 0.f, 0.f, 0.f}, o1 = {0.f, 0.f, 0.f, 0.f};
  floatx4 o2 = {0.f, 0.f, 0.f, 0.f}, o3 = {0.f, 0.f, 0.f, 0.f};

  const bool lo_half = (lg < 2);
  const bool sndR = (lg == 0) || (lg == 3);

#pragma unroll
  for (int win = 0; win < 8; ++win) {
    const int k0 = ksb + win * 32;
    unsigned uA0, uA1, uB0, uB1;
    // iter A: k rows [k0, k0+16)
    {
      short8 kA = *(const short8*)(kp + (size_t)k0 * ND);
      short8 kB = *(const short8*)(kp + (size_t)k0 * ND + 32);
      floatx4 bV = *(const floatx4*)(bp + k0);
      intx4 mV = *(const intx4*)(mp + k0);
      floatx4 c = bV;
      c = __builtin_amdgcn_mfma_f32_16x16x32_bf16(kA, aq0, c, 0, 0, 0);
      c = __builtin_amdgcn_mfma_f32_16x16x32_bf16(kB, aq1, c, 0, 0, 0);
      float p0 = mV[0] ? __expf(c[0]) * inv : 0.f;
      float p1 = mV[1] ? __expf(c[1]) * inv : 0.f;
      float p2 = mV[2] ? __expf(c[2]) * inv : 0.f;
      float p3 = mV[3] ? __expf(c[3]) * inv : 0.f;
      uA0 = (unsigned)f2bf(p0) | ((unsigned)f2bf(p1) << 16);
      uA1 = (unsigned)f2bf(p2) | ((unsigned)f2bf(p3) << 16);
    }
    // iter B: k rows [k0+16, k0+32)
    {
      const int k1 = k0 + 16;
      short8 kA = *(const short8*)(kp + (size_t)k1 * ND);
      short8 kB = *(const short8*)(kp + (size_t)k1 * ND + 32);
      floatx4 bV = *(const floatx4*)(bp + k1);
      intx4 mV = *(const intx4*)(mp + k1);
      floatx4 c = bV;
      c = __builtin_amdgcn_mfma_f32_16x16x32_bf16(kA, aq0, c, 0, 0, 0);
      c = __builtin_amdgcn_mfma_f32_16x16x32_bf16(kB, aq1, c, 0, 0, 0);
      float p0 = mV[0] ? __expf(c[0]) * inv : 0.f;
      float p1 = mV[1] ? __expf(c[1]) * inv : 0.f;
      float p2 = mV[2] ? __expf(c[2]) * inv : 0.f;
      float p3 = mV[3] ? __expf(c[3]) * inv : 0.f;
      uB0 = (unsigned)f2bf(p0) | ((unsigned)f2bf(p1) << 16);
      uB1 = (unsigned)f2bf(p2) | ((unsigned)f2bf(p3) << 16);
    }
    // 2-round shuffle transpose among lanes {lc, lc+16, lc+32, lc+48}:
    // pre: lane lg holds P[row lc][k = {lg4..lg4+3} and {16+lg4..16+lg4+3}]
    // post: lane lg holds P[row lc][k = lg8..lg8+7]  (= PV A-frag slots)
    unsigned ma = lo_half ? uA0 : uB0;
    unsigned mb = lo_half ? uA1 : uB1;
    unsigned sa = lo_half ? uB0 : uA0;
    unsigned sb = lo_half ? uB1 : uA1;
    unsigned r1a = __shfl_xor(sa, 32);
    unsigned r1b = __shfl_xor(sb, 32);
    unsigned s2a = sndR ? r1a : ma;
    unsigned s2b = sndR ? r1b : mb;
    unsigned g2a = __shfl_xor(s2a, 16);
    unsigned g2b = __shfl_xor(s2b, 16);
    unsigned t0 = (lg == 0) ? ma : (lg == 2) ? r1a : g2a;
    unsigned t1 = (lg == 0) ? mb : (lg == 2) ? r1b : g2b;
    unsigned t2 = (lg == 1) ? r1a : (lg == 3) ? ma : g2a;
    unsigned t3 = (lg == 1) ? r1b : (lg == 3) ? mb : g2b;

    // normalized attn write: row lc, k = k0+lg8 .. +7 (32B/lane, 128B/row)
    floatx4 fa, fb;
    fa[0] = bf2f(t0 & 0xffffu); fa[1] = bf2f(t0 >> 16);
    fa[2] = bf2f(t1 & 0xffffu); fa[3] = bf2f(t1 >> 16);
    fb[0] = bf2f(t2 & 0xffffu); fb[1] = bf2f(t2 >> 16);
    fb[2] = bf2f(t3 & 0xffffu); fb[3] = bf2f(t3 >> 16);
    __builtin_nontemporal_store(fa, (floatx4*)(arow + k0));
    __builtin_nontemporal_store(fb, (floatx4*)(arow + k0 + 4));

    // PV: pa is exactly the A-frag for this 32-k window
    uintx4 uu; uu[0] = t0; uu[1] = t1; uu[2] = t2; uu[3] = t3;
    short8 pa = __builtin_bit_cast(short8, uu);
    short8 vb0 = *(const short8*)(vp + (size_t)(0 * 16) * NS + k0);
    short8 vb1 = *(const short8*)(vp + (size_t)(1 * 16) * NS + k0);
    short8 vb2 = *(const short8*)(vp + (size_t)(2 * 16) * NS + k0);
    short8 vb3 = *(const short8*)(vp + (size_t)(3 * 16) * NS + k0);
    o0 = __builtin_amdgcn_mfma_f32_16x16x32_bf16(pa, vb0, o0, 0, 0, 0);
    o1 = __builtin_amdgcn_mfma_f32_16x16x32_bf16(pa, vb1, o1, 0, 0, 0);
    o2 = __builtin_amdgcn_mfma_f32_16x16x32_bf16(pa, vb2, o2, 0, 0, 0);
    o3 = __builtin_amdgcn_mfma_f32_16x16x32_bf16(pa, vb3, o3, 0, 0, 0);
  }

  // O-reduce across the 8 waves (only barriers in the kernel)
#pragma unroll
  for (int r = 0; r < 4; ++r) {
    Ored[wave][lg4 + r][0 * 16 + lc] = o0[r];
    Ored[wave][lg4 + r][1 * 16 + lc] = o1[r];
    Ored[wave][lg4 + r][2 * 16 + lc] = o2[r];
    Ored[wave][lg4 + r][3 * 16 + lc] = o3[r];
  }
  __syncthreads();
  {
    const int q = tid >> 5;          // 0..15
    const int c2 = (tid & 31) * 2;   // 0..62
    float a0 = 0.f, a1 = 0.f;
#pragma unroll
    for (int w = 0; w < 8; ++w) {
      a0 += Ored[w][q][c2];
      a1 += Ored[w][q][c2 + 1];
    }
    __builtin_nontemporal_store(a0, out + (bh * NS + (size_t)(q0 + q)) * ND + c2);
    __builtin_nontemporal_store(a1, out + (bh * NS + (size_t)(q0 + q)) * ND + c2 + 1);
  }
}

extern "C" void kernel_launch(void* const* d_in, const int* in_sizes, int n_in,
                              void* d_out, int out_size, void* d_ws, size_t ws_size,
                              hipStream_t stream) {
  const float* Q = (const float*)d_in[0];
  const float* K = (const float*)d_in[1];
  const float* V = (const float*)d_in[2];
  const int* mask = (const int*)d_in[3];
  const float* bias = (const float*)d_in[4];

  float* out = (float*)d_out;
  float* attn = out + (size_t)NB * NH * NS * ND;  // outputs concatenated: (output, attn)

  unsigned short* kb = (unsigned short*)d_ws;                      // 16.8 MB
  unsigned short* vt = kb + (size_t)NB * NH * NS * ND;             // 16.8 MB
  float* rs = (float*)(vt + (size_t)NB * NH * NS * ND);            // 0.5 MB rowsums

  prep_k_kernel<<<(NB * NH * NS * ND) / (256 * 4), 256, 0, stream>>>(K, kb);
  prep_vt_kernel<<<NB * NH * (NS / 64), 256, 0, stream>>>(V, vt);
  sum_kernel<<<NB * NH * (NS / 16), 512, 0, stream>>>(Q, kb, mask, bias, rs);
  attn_kernel<<<NB * NH * (NS / 16), 512, 0, stream>>>(Q, kb, vt, mask, bias, rs, out, attn);
}

// Round 6
// 818.672 us; speedup vs baseline: 1.4834x; 1.4834x over previous
//
#include <hip/hip_runtime.h>

#define NB 4
#define NH 16
#define NS 2048
#define ND 64

typedef __attribute__((ext_vector_type(8))) short short8;
typedef __attribute__((ext_vector_type(4))) float floatx4;
typedef __attribute__((ext_vector_type(2))) float floatx2;
typedef __attribute__((ext_vector_type(4))) int intx4;
typedef __attribute__((ext_vector_type(4))) unsigned uintx4;

#define MFMA __builtin_amdgcn_mfma_f32_16x16x32_bf16

__device__ __forceinline__ unsigned short f2bf(float f) {
  unsigned u = __builtin_bit_cast(unsigned, f);
  u = (u + 0x7FFFu + ((u >> 16) & 1u)) >> 16;  // RNE
  return (unsigned short)u;
}
__device__ __forceinline__ float bf2f(unsigned u16) {
  unsigned u = u16 << 16;
  return __builtin_bit_cast(float, u);
}

// ---- prep: K fp32 -> bf16, same [b,h,k,d] layout ----
__global__ __launch_bounds__(256) void prep_k_kernel(const float* __restrict__ K,
                                                     unsigned short* __restrict__ kb) {
  size_t i = ((size_t)blockIdx.x * 256 + threadIdx.x) * 4;
  floatx4 v = *(const floatx4*)(K + i);
  unsigned long long o = 0;
  o |= (unsigned long long)f2bf(v[0]);
  o |= (unsigned long long)f2bf(v[1]) << 16;
  o |= (unsigned long long)f2bf(v[2]) << 32;
  o |= (unsigned long long)f2bf(v[3]) << 48;
  *(unsigned long long*)(kb + i) = o;
}

// ---- prep: V [bh][k][d] fp32 -> VT [bh][d][k] bf16 ----
__global__ __launch_bounds__(256) void prep_vt_kernel(const float* __restrict__ V,
                                                      unsigned short* __restrict__ vt) {
  __shared__ float tile[64][65];
  int kc = blockIdx.x & 31;
  int bh = blockIdx.x >> 5;
  int k0 = kc * 64;
  const float* src = V + ((size_t)bh * NS + k0) * ND;
  int t = threadIdx.x;
  int r0 = t >> 4;
  int c = (t & 15) * 4;
  for (int rr = 0; rr < 4; ++rr) {
    int r = rr * 16 + r0;
    floatx4 v = *(const floatx4*)(src + (size_t)r * ND + c);
    tile[r][c + 0] = v[0]; tile[r][c + 1] = v[1];
    tile[r][c + 2] = v[2]; tile[r][c + 3] = v[3];
  }
  __syncthreads();
  unsigned short* dst = vt + (size_t)bh * ND * NS + k0;
  for (int i = 0; i < 16; ++i) {
    int lin = i * 256 + t;
    int d = lin >> 6, k = lin & 63;
    dst[(size_t)d * NS + k] = f2bf(tile[k][d]);
  }
}

// ---- fused attention, P in registers ----
// 16-row q-tile, 512 threads = 8 waves; wave w owns k-strip [256w, 256w+256).
// Swapped QK (mfma(K,Q)) -> C[k][q]; shuffle-transpose -> P regs (row lc, k lg8..).
// amdgpu_waves_per_eu(3,4): scheduler targets <=4 waves/EU -> 128+ VGPR budget,
// so it can hoist loads for latency hiding instead of sinking to 64-VGPR/8-wave.
__global__ void __attribute__((amdgpu_flat_work_group_size(512, 512),
                               amdgpu_waves_per_eu(3, 4)))
attn_kernel(
    const float* __restrict__ Q,
    const unsigned short* __restrict__ Kb,
    const unsigned short* __restrict__ VT,
    const int* __restrict__ mask,
    const float* __restrict__ bias,
    float* __restrict__ out,
    float* __restrict__ attn) {
  __shared__ float sums[8][16];
  __shared__ float Ored[8][16][68];  // padded: rows 4 apart -> +16 banks (2-way max)

  const int bid = blockIdx.x;
  const int b = bid & 3;                // batch fastest -> bias tile shared via L2/L3
  const int qt = (bid >> 2) & 127;
  const int h = bid >> 9;
  const int q0 = qt * 16;

  const int tid = threadIdx.x;
  const int wave = tid >> 6;  // 0..7, k-strip [256w, 256w+256)
  const int lane = tid & 63;
  const int lg = lane >> 4;
  const int lc = lane & 15;
  const int lg4 = lg * 4;
  const int lg8 = lg * 8;
  const size_t bh = (size_t)(b * NH + h);

  // Q B-frags (n = q = lc), 1/8 scale folded into bf16 convert (2^-3 exact)
  short8 aq0, aq1;
  {
    const float* qrow = Q + (bh * NS + (size_t)(q0 + lc)) * ND + lg8;
    floatx4 f0 = *(const floatx4*)(qrow);
    floatx4 f1 = *(const floatx4*)(qrow + 4);
    floatx4 f2 = *(const floatx4*)(qrow + 32);
    floatx4 f3 = *(const floatx4*)(qrow + 36);
#pragma unroll
    for (int j = 0; j < 4; ++j) {
      aq0[j] = (short)f2bf(f0[j] * 0.125f);
      aq0[4 + j] = (short)f2bf(f1[j] * 0.125f);
      aq1[j] = (short)f2bf(f2[j] * 0.125f);
      aq1[4 + j] = (short)f2bf(f3[j] * 0.125f);
    }
  }

  const unsigned short* kp = Kb + bh * NS * ND + (size_t)lc * ND + lg8;
  const float* bp = bias + ((size_t)h * NS + (size_t)(q0 + lc)) * NS + lg4;
  const int* mp = mask + b * NS + lg4;
  const unsigned short* vp = VT + bh * (size_t)ND * NS + (size_t)lc * NS + lg8;
  float* arow = attn + (bh * NS + (size_t)(q0 + lc)) * NS + lg8;
  const int ksb = wave * 256;

  const bool lo_half = (lg < 2);
  const bool sndR = (lg == 0) || (lg == 3);
  float psum = 0.f;

  // ---- phase 1: QK^T + bias + mask + exp -> P packed bf16 in registers ----
#define QKWIN(W)                                                          \
  uintx4 pw##W;                                                           \
  {                                                                       \
    const int kk = ksb + (W) * 32;                                        \
    unsigned uA0, uA1, uB0, uB1;                                          \
    {                                                                     \
      short8 kA = *(const short8*)(kp + (size_t)kk * ND);                 \
      short8 kB = *(const short8*)(kp + (size_t)kk * ND + 32);            \
      floatx4 bV = *(const floatx4*)(bp + kk);                            \
      intx4 mV = *(const intx4*)(mp + kk);                                \
      floatx4 c = bV;                                                     \
      c = MFMA(kA, aq0, c, 0, 0, 0);                                      \
      c = MFMA(kB, aq1, c, 0, 0, 0);                                      \
      float p0 = mV[0] ? __expf(c[0]) : 0.f;                              \
      float p1 = mV[1] ? __expf(c[1]) : 0.f;                              \
      float p2 = mV[2] ? __expf(c[2]) : 0.f;                              \
      float p3 = mV[3] ? __expf(c[3]) : 0.f;                              \
      psum += (p0 + p1) + (p2 + p3);                                      \
      uA0 = (unsigned)f2bf(p0) | ((unsigned)f2bf(p1) << 16);              \
      uA1 = (unsigned)f2bf(p2) | ((unsigned)f2bf(p3) << 16);              \
    }                                                                     \
    {                                                                     \
      const int k1 = kk + 16;                                             \
      short8 kA = *(const short8*)(kp + (size_t)k1 * ND);                 \
      short8 kB = *(const short8*)(kp + (size_t)k1 * ND + 32);            \
      floatx4 bV = *(const floatx4*)(bp + k1);                            \
      intx4 mV = *(const intx4*)(mp + k1);                                \
      floatx4 c = bV;                                                     \
      c = MFMA(kA, aq0, c, 0, 0, 0);                                      \
      c = MFMA(kB, aq1, c, 0, 0, 0);                                      \
      float p0 = mV[0] ? __expf(c[0]) : 0.f;                              \
      float p1 = mV[1] ? __expf(c[1]) : 0.f;                              \
      float p2 = mV[2] ? __expf(c[2]) : 0.f;                              \
      float p3 = mV[3] ? __expf(c[3]) : 0.f;                              \
      psum += (p0 + p1) + (p2 + p3);                                      \
      uB0 = (unsigned)f2bf(p0) | ((unsigned)f2bf(p1) << 16);              \
      uB1 = (unsigned)f2bf(p2) | ((unsigned)f2bf(p3) << 16);              \
    }                                                                     \
    /* 4-lane transpose: (q=lc, k=lg4-based x2) -> (q=lc, k=lg8..lg8+7) */ \
    unsigned ma = lo_half ? uA0 : uB0;                                    \
    unsigned mb = lo_half ? uA1 : uB1;                                    \
    unsigned sa = lo_half ? uB0 : uA0;                                    \
    unsigned sb = lo_half ? uB1 : uA1;                                    \
    unsigned r1a = __shfl_xor(sa, 32);                                    \
    unsigned r1b = __shfl_xor(sb, 32);                                    \
    unsigned s2a = sndR ? r1a : ma;                                       \
    unsigned s2b = sndR ? r1b : mb;                                       \
    unsigned g2a = __shfl_xor(s2a, 16);                                   \
    unsigned g2b = __shfl_xor(s2b, 16);                                   \
    pw##W[0] = (lg == 0) ? ma : (lg == 2) ? r1a : g2a;                    \
    pw##W[1] = (lg == 0) ? mb : (lg == 2) ? r1b : g2b;                    \
    pw##W[2] = (lg == 1) ? r1a : (lg == 3) ? ma : g2a;                    \
    pw##W[3] = (lg == 1) ? r1b : (lg == 3) ? mb : g2b;                    \
  }

  QKWIN(0) QKWIN(1) QKWIN(2) QKWIN(3)
  QKWIN(4) QKWIN(5) QKWIN(6) QKWIN(7)
#undef QKWIN

  // rowsum: lanes {l, l^16, l^32, l^48} share q=lc
  psum += __shfl_xor(psum, 16);
  psum += __shfl_xor(psum, 32);
  if (lane < 16) sums[wave][lane] = psum;
  __syncthreads();

  float inv;  // 1 / rowsum for q = lc (attn-store scaling)
  {
    float t = 0.f;
#pragma unroll
    for (int w = 0; w < 8; ++w) t += sums[w][lc];
    inv = 1.f / t;
  }

  // ---- phase 2: unpack P regs -> scaled attn nt-stores + PV MFMA (unscaled) ----
  floatx4 o0 = {0.f, 0.f, 0.f, 0.f}, o1 = {0.f, 0.f, 0.f, 0.f};
  floatx4 o2 = {0.f, 0.f, 0.f, 0.f}, o3 = {0.f, 0.f, 0.f, 0.f};

#define PVWIN(W)                                                          \
  {                                                                       \
    const int kk = ksb + (W) * 32;                                        \
    short8 vb0 = *(const short8*)(vp + (size_t)(0 * 16) * NS + kk);       \
    short8 vb1 = *(const short8*)(vp + (size_t)(1 * 16) * NS + kk);       \
    short8 vb2 = *(const short8*)(vp + (size_t)(2 * 16) * NS + kk);       \
    short8 vb3 = *(const short8*)(vp + (size_t)(3 * 16) * NS + kk);       \
    floatx4 fa, fb;                                                       \
    fa[0] = bf2f(pw##W[0] & 0xffffu) * inv;                               \
    fa[1] = bf2f(pw##W[0] >> 16) * inv;                                   \
    fa[2] = bf2f(pw##W[1] & 0xffffu) * inv;                               \
    fa[3] = bf2f(pw##W[1] >> 16) * inv;                                   \
    fb[0] = bf2f(pw##W[2] & 0xffffu) * inv;                               \
    fb[1] = bf2f(pw##W[2] >> 16) * inv;                                   \
    fb[2] = bf2f(pw##W[3] & 0xffffu) * inv;                               \
    fb[3] = bf2f(pw##W[3] >> 16) * inv;                                   \
    __builtin_nontemporal_store(fa, (floatx4*)(arow + kk));               \
    __builtin_nontemporal_store(fb, (floatx4*)(arow + kk + 4));           \
    short8 pa = __builtin_bit_cast(short8, pw##W);                        \
    o0 = MFMA(pa, vb0, o0, 0, 0, 0);                                      \
    o1 = MFMA(pa, vb1, o1, 0, 0, 0);                                      \
    o2 = MFMA(pa, vb2, o2, 0, 0, 0);                                      \
    o3 = MFMA(pa, vb3, o3, 0, 0, 0);                                      \
  }

  PVWIN(0) PVWIN(1) PVWIN(2) PVWIN(3)
  PVWIN(4) PVWIN(5) PVWIN(6) PVWIN(7)
#undef PVWIN

  // ---- O-reduce across 8 waves; normalization folded in here ----
#pragma unroll
  for (int r = 0; r < 4; ++r) {
    Ored[wave][lg4 + r][0 * 16 + lc] = o0[r];
    Ored[wave][lg4 + r][1 * 16 + lc] = o1[r];
    Ored[wave][lg4 + r][2 * 16 + lc] = o2[r];
    Ored[wave][lg4 + r][3 * 16 + lc] = o3[r];
  }
  __syncthreads();
  {
    const int q = tid >> 5;          // 0..15
    const int c2 = (tid & 31) * 2;   // 0..62
    float a0 = 0.f, a1 = 0.f;
#pragma unroll
    for (int w = 0; w < 8; ++w) {
      a0 += Ored[w][q][c2];
      a1 += Ored[w][q][c2 + 1];
    }
    float tot = 0.f;
#pragma unroll
    for (int w = 0; w < 8; ++w) tot += sums[w][q];
    const float invq = 1.f / tot;
    floatx2 res;
    res[0] = a0 * invq;
    res[1] = a1 * invq;
    __builtin_nontemporal_store(res, (floatx2*)(out + (bh * NS + (size_t)(q0 + q)) * ND + c2));
  }
}

extern "C" void kernel_launch(void* const* d_in, const int* in_sizes, int n_in,
                              void* d_out, int out_size, void* d_ws, size_t ws_size,
                              hipStream_t stream) {
  const float* Q = (const float*)d_in[0];
  const float* K = (const float*)d_in[1];
  const float* V = (const float*)d_in[2];
  const int* mask = (const int*)d_in[3];
  const float* bias = (const float*)d_in[4];

  float* out = (float*)d_out;
  float* attn = out + (size_t)NB * NH * NS * ND;  // outputs concatenated: (output, attn)

  unsigned short* kb = (unsigned short*)d_ws;                      // 16.8 MB
  unsigned short* vt = kb + (size_t)NB * NH * NS * ND;             // 16.8 MB

  prep_k_kernel<<<(NB * NH * NS * ND) / (256 * 4), 256, 0, stream>>>(K, kb);
  prep_vt_kernel<<<NB * NH * (NS / 64), 256, 0, stream>>>(V, vt);
  attn_kernel<<<NB * NH * (NS / 16), 512, 0, stream>>>(Q, kb, vt, mask, bias, out, attn);
}

// Round 7
// 641.663 us; speedup vs baseline: 1.8926x; 1.2759x over previous
//
#include <hip/hip_runtime.h>

#define NB 4
#define NH 16
#define NS 2048
#define ND 64

typedef __attribute__((ext_vector_type(8))) short short8;
typedef __attribute__((ext_vector_type(4))) float floatx4;
typedef __attribute__((ext_vector_type(4))) int intx4;
typedef __attribute__((ext_vector_type(4))) unsigned uintx4;

#define MFMA __builtin_amdgcn_mfma_f32_16x16x32_bf16
#define WAITV(N) asm volatile("s_waitcnt vmcnt(" #N ")" ::: "memory")
#define WAITL asm volatile("s_waitcnt lgkmcnt(0)" ::: "memory")

__device__ __forceinline__ unsigned short f2bf(float f) {
  unsigned u = __builtin_bit_cast(unsigned, f);
  u = (u + 0x7FFFu + ((u >> 16) & 1u)) >> 16;  // RNE
  return (unsigned short)u;
}
__device__ __forceinline__ float bf2f(unsigned u16) {
  unsigned u = u16 << 16;
  return __builtin_bit_cast(float, u);
}
// async global->LDS, 16B/lane, LDS dest = wave-uniform base + lane*16
__device__ __forceinline__ void gload16(const void* g, void* l) {
  __builtin_amdgcn_global_load_lds(
      (const __attribute__((address_space(1))) unsigned int*)g,
      (__attribute__((address_space(3))) unsigned int*)l, 16, 0, 0);
}

// ---- prep: K fp32 -> bf16, same [b,h,k,d] layout ----
__global__ __launch_bounds__(256) void prep_k_kernel(const float* __restrict__ K,
                                                     unsigned short* __restrict__ kb) {
  size_t i = ((size_t)blockIdx.x * 256 + threadIdx.x) * 4;
  floatx4 v = *(const floatx4*)(K + i);
  unsigned long long o = 0;
  o |= (unsigned long long)f2bf(v[0]);
  o |= (unsigned long long)f2bf(v[1]) << 16;
  o |= (unsigned long long)f2bf(v[2]) << 32;
  o |= (unsigned long long)f2bf(v[3]) << 48;
  *(unsigned long long*)(kb + i) = o;
}

// ---- prep: V [bh][k][d] fp32 -> VT [bh][d][k] bf16 ----
__global__ __launch_bounds__(256) void prep_vt_kernel(const float* __restrict__ V,
                                                      unsigned short* __restrict__ vt) {
  __shared__ float tile[64][65];
  int kc = blockIdx.x & 31;
  int bh = blockIdx.x >> 5;
  int k0 = kc * 64;
  const float* src = V + ((size_t)bh * NS + k0) * ND;
  int t = threadIdx.x;
  int r0 = t >> 4;
  int c = (t & 15) * 4;
  for (int rr = 0; rr < 4; ++rr) {
    int r = rr * 16 + r0;
    floatx4 v = *(const floatx4*)(src + (size_t)r * ND + c);
    tile[r][c + 0] = v[0]; tile[r][c + 1] = v[1];
    tile[r][c + 2] = v[2]; tile[r][c + 3] = v[3];
  }
  __syncthreads();
  unsigned short* dst = vt + (size_t)bh * ND * NS + k0;
  for (int i = 0; i < 16; ++i) {
    int lin = i * 256 + t;
    int d = lin >> 6, k = lin & 63;
    dst[(size_t)d * NS + k] = f2bf(tile[k][d]);
  }
}

// ---- prep: mask -> bit-packed words (1 bit per k) ----
__global__ __launch_bounds__(256) void prep_mask_kernel(const int* __restrict__ mask,
                                                        unsigned* __restrict__ mb) {
  int t = blockIdx.x * 256 + threadIdx.x;  // 256 words = NB * NS/32
  const int* mp = mask + t * 32;
  unsigned w = 0;
#pragma unroll
  for (int i = 0; i < 32; ++i) w |= (mp[i] != 0 ? 1u : 0u) << i;
  mb[t] = w;
}

// ---- fused attention, global_load_lds pipelined, P in registers ----
// 256 threads = 4 waves; q-tile 16; wave w owns k-strip [512w, 512w+512).
// Per wave: dbuf LDS staging of K(4KB)+bias(2KB) subtiles, counted vmcnt(6),
// no barriers in main loops. XOR-swizzled both-sides (rule 21).
__global__ void __attribute__((amdgpu_flat_work_group_size(256, 256),
                               amdgpu_waves_per_eu(3, 4)))
attn_kernel(
    const float* __restrict__ Q,
    const unsigned short* __restrict__ Kb,
    const unsigned short* __restrict__ VT,
    const unsigned* __restrict__ maskbits,
    const float* __restrict__ bias,
    float* __restrict__ out,
    float* __restrict__ attn) {
  extern __shared__ char smem[];
  // per-wave staging: wave*12288: K slot0/1 @0/4096, bias slot0/1 @8192/10240
  // sums @49152 (4 waves x 16 rows); Ored aliases [0,18432) after syncthreads

  const int bid = blockIdx.x;
  const int b = bid & 3;                // batch fastest -> bias tile L2/L3-shared
  const int qt = (bid >> 2) & 127;
  const int h = bid >> 9;
  const int q0 = qt * 16;

  const int tid = threadIdx.x;
  const int wave = tid >> 6;  // 0..3
  const int lane = tid & 63;
  const int lg = lane >> 4;
  const int lc = lane & 15;
  const int lg4 = lg * 4;
  const int lg8 = lg * 8;
  const size_t bh = (size_t)(b * NH + h);

  char* smStage = smem + wave * 12288;
  float* sums = (float*)(smem + 49152);

  // Q B-frags (n = q = lc), 1/8 scale folded into bf16 convert (2^-3 exact)
  short8 aq0, aq1;
  {
    const float* qrow = Q + (bh * NS + (size_t)(q0 + lc)) * ND + lg8;
    floatx4 f0 = *(const floatx4*)(qrow);
    floatx4 f1 = *(const floatx4*)(qrow + 4);
    floatx4 f2 = *(const floatx4*)(qrow + 32);
    floatx4 f3 = *(const floatx4*)(qrow + 36);
#pragma unroll
    for (int j = 0; j < 4; ++j) {
      aq0[j] = (short)f2bf(f0[j] * 0.125f);
      aq0[4 + j] = (short)f2bf(f1[j] * 0.125f);
      aq1[j] = (short)f2bf(f2[j] * 0.125f);
      aq1[4 + j] = (short)f2bf(f3[j] * 0.125f);
    }
  }
  const int ksb = wave * 512;
  // mask bits for this wave's 512-k strip: 16 uniform words
  intx4 mva, mvb, mvc, mvd;
  {
    const intx4* mp = (const intx4*)(maskbits + b * (NS / 32) + wave * 16);
    mva = mp[0]; mvb = mp[1]; mvc = mp[2]; mvd = mp[3];
  }

  // staging source pointers (pre-swizzled global addresses; LDS stays linear)
  const int kj = (lane & 7) ^ (lane >> 3);            // 128B rows, 8 chunks
  const unsigned short* kRowPtr = Kb + bh * NS * ND + (size_t)(lane >> 3) * ND + kj * 8;
  const float* bRowPtr = bias + ((size_t)h * NS + (size_t)(q0 + (lane >> 3))) * NS + kj * 4;
  const int vj = (lane & 3) ^ ((lane >> 2) & 3);      // 64B rows, 4 chunks
  const unsigned short* vRowPtr = VT + bh * (size_t)ND * NS + (size_t)(lane >> 2) * NS + vj * 8;

  // swizzled read offsets (byte): involution XOR by (row & 7) / (row & 3)
  const int lc128 = lc * 128;
  const int kRd0 = ((lg ^ (lc & 7)) * 16);
  const int kRd1 = (((4 + lg) ^ (lc & 7)) * 16);
  const int vRd = ((lg ^ (lc & 3)) * 16);

  const bool lo_half = (lg < 2);
  const bool sndR = (lg == 0) || (lg == 3);
  float psum = 0.f;

  asm volatile("s_waitcnt vmcnt(0)" ::: "memory");  // Q/mask loads retired; count = 0

#define KISSUE(IT, SLOT) {                                                \
    const int k0_ = ksb + (IT) * 32;                                      \
    const unsigned short* ks_ = kRowPtr + (size_t)k0_ * ND;               \
    char* kd_ = smStage + (SLOT) * 4096;                                  \
    gload16(ks_, kd_);                                                    \
    gload16(ks_ + 8 * ND, kd_ + 1024);                                    \
    gload16(ks_ + 16 * ND, kd_ + 2048);                                   \
    gload16(ks_ + 24 * ND, kd_ + 3072);                                   \
    const float* bs_ = bRowPtr + k0_;                                     \
    char* bd_ = smStage + 8192 + (SLOT) * 2048;                           \
    gload16(bs_, bd_);                                                    \
    gload16(bs_ + 8 * NS, bd_ + 1024);                                    \
  }

#define SUBTILE(IT, SLOT, NW, MW)                                         \
  uintx4 pw##IT;                                                          \
  {                                                                       \
    WAITV(NW);                                                            \
    const char* kb_ = smStage + (SLOT) * 4096;                            \
    const char* bb_ = smStage + 8192 + (SLOT) * 2048;                     \
    short8 kA0 = *(const short8*)(kb_ + lc128 + kRd0);                    \
    short8 kB0 = *(const short8*)(kb_ + lc128 + kRd1);                    \
    short8 kA1 = *(const short8*)(kb_ + 2048 + lc128 + kRd0);             \
    short8 kB1 = *(const short8*)(kb_ + 2048 + lc128 + kRd1);             \
    floatx4 bV0 = *(const floatx4*)(bb_ + lc128 + kRd0);                  \
    floatx4 bV1 = *(const floatx4*)(bb_ + lc128 + kRd1);                  \
    unsigned uA0, uA1, uB0, uB1;                                          \
    {                                                                     \
      floatx4 c = bV0;                                                    \
      c = MFMA(kA0, aq0, c, 0, 0, 0);                                     \
      c = MFMA(kB0, aq1, c, 0, 0, 0);                                     \
      unsigned mb_ = (MW) >> lg4;                                         \
      float p0 = (mb_ & 1u) ? __expf(c[0]) : 0.f;                         \
      float p1 = (mb_ & 2u) ? __expf(c[1]) : 0.f;                         \
      float p2 = (mb_ & 4u) ? __expf(c[2]) : 0.f;                         \
      float p3 = (mb_ & 8u) ? __expf(c[3]) : 0.f;                         \
      psum += (p0 + p1) + (p2 + p3);                                      \
      uA0 = (unsigned)f2bf(p0) | ((unsigned)f2bf(p1) << 16);              \
      uA1 = (unsigned)f2bf(p2) | ((unsigned)f2bf(p3) << 16);              \
    }                                                                     \
    {                                                                     \
      floatx4 c = bV1;                                                    \
      c = MFMA(kA1, aq0, c, 0, 0, 0);                                     \
      c = MFMA(kB1, aq1, c, 0, 0, 0);                                     \
      unsigned mb_ = (MW) >> (16 + lg4);                                  \
      float p0 = (mb_ & 1u) ? __expf(c[0]) : 0.f;                         \
      float p1 = (mb_ & 2u) ? __expf(c[1]) : 0.f;                         \
      float p2 = (mb_ & 4u) ? __expf(c[2]) : 0.f;                         \
      float p3 = (mb_ & 8u) ? __expf(c[3]) : 0.f;                         \
      psum += (p0 + p1) + (p2 + p3);                                      \
      uB0 = (unsigned)f2bf(p0) | ((unsigned)f2bf(p1) << 16);              \
      uB1 = (unsigned)f2bf(p2) | ((unsigned)f2bf(p3) << 16);              \
    }                                                                     \
    unsigned ma = lo_half ? uA0 : uB0;                                    \
    unsigned mb2 = lo_half ? uA1 : uB1;                                   \
    unsigned sa = lo_half ? uB0 : uA0;                                    \
    unsigned sb = lo_half ? uB1 : uA1;                                    \
    unsigned r1a = __shfl_xor(sa, 32);                                    \
    unsigned r1b = __shfl_xor(sb, 32);                                    \
    unsigned s2a = sndR ? r1a : ma;                                       \
    unsigned s2b = sndR ? r1b : mb2;                                      \
    unsigned g2a = __shfl_xor(s2a, 16);                                   \
    unsigned g2b = __shfl_xor(s2b, 16);                                   \
    pw##IT[0] = (lg == 0) ? ma : (lg == 2) ? r1a : g2a;                   \
    pw##IT[1] = (lg == 0) ? mb2 : (lg == 2) ? r1b : g2b;                  \
    pw##IT[2] = (lg == 1) ? r1a : (lg == 3) ? ma : g2a;                   \
    pw##IT[3] = (lg == 1) ? r1b : (lg == 3) ? mb2 : g2b;                  \
    WAITL;                                                                \
  }

  KISSUE(0, 0) KISSUE(1, 1)
  SUBTILE(0, 0, 6, mva[0])  KISSUE(2, 0)
  SUBTILE(1, 1, 6, mva[1])  KISSUE(3, 1)
  SUBTILE(2, 0, 6, mva[2])  KISSUE(4, 0)
  SUBTILE(3, 1, 6, mva[3])  KISSUE(5, 1)
  SUBTILE(4, 0, 6, mvb[0])  KISSUE(6, 0)
  SUBTILE(5, 1, 6, mvb[1])  KISSUE(7, 1)
  SUBTILE(6, 0, 6, mvb[2])  KISSUE(8, 0)
  SUBTILE(7, 1, 6, mvb[3])  KISSUE(9, 1)
  SUBTILE(8, 0, 6, mvc[0])  KISSUE(10, 0)
  SUBTILE(9, 1, 6, mvc[1])  KISSUE(11, 1)
  SUBTILE(10, 0, 6, mvc[2]) KISSUE(12, 0)
  SUBTILE(11, 1, 6, mvc[3]) KISSUE(13, 1)
  SUBTILE(12, 0, 6, mvd[0]) KISSUE(14, 0)
  SUBTILE(13, 1, 6, mvd[1]) KISSUE(15, 1)
  SUBTILE(14, 0, 6, mvd[2])
  SUBTILE(15, 1, 0, mvd[3])
#undef SUBTILE
#undef KISSUE

#define VISSUE(W, SLOT) {                                                 \
    const int kk_ = ksb + (W) * 32;                                       \
    const unsigned short* vs_ = vRowPtr + kk_;                            \
    char* vd_ = smStage + (SLOT) * 4096;                                  \
    gload16(vs_, vd_);                                                    \
    gload16(vs_ + 16 * NS, vd_ + 1024);                                   \
    gload16(vs_ + 32 * NS, vd_ + 2048);                                   \
    gload16(vs_ + 48 * NS, vd_ + 3072);                                   \
  }

  // rowsum exchange: lanes {l, l^16, l^32, l^48} share q = lc
  psum += __shfl_xor(psum, 16);
  psum += __shfl_xor(psum, 32);
  if (lane < 16) sums[wave * 16 + lane] = psum;
  VISSUE(0, 0) VISSUE(1, 1)   // prefetch rides across the raw barrier
  WAITL;
  __builtin_amdgcn_sched_barrier(0);
  __builtin_amdgcn_s_barrier();  // raw: vmcnt NOT drained
  __builtin_amdgcn_sched_barrier(0);
  float inv;
  {
    float t = sums[0 * 16 + lc] + sums[1 * 16 + lc] + sums[2 * 16 + lc] + sums[3 * 16 + lc];
    inv = 1.f / t;
  }

  floatx4 o0 = {0.f, 0.f, 0.f, 0.f}, o1 = {0.f, 0.f, 0.f, 0.f};
  floatx4 o2 = {0.f, 0.f, 0.f, 0.f}, o3 = {0.f, 0.f, 0.f, 0.f};
  float* arow = attn + (bh * NS + (size_t)(q0 + lc)) * NS + lg8;

#define PVWIN(W, SLOT, NW) {                                              \
    WAITV(NW);                                                            \
    const char* vb_ = smStage + (SLOT) * 4096;                            \
    short8 vb0 = *(const short8*)(vb_ + (0 * 16 + lc) * 64 + vRd);        \
    short8 vb1 = *(const short8*)(vb_ + (1 * 16 + lc) * 64 + vRd);        \
    short8 vb2 = *(const short8*)(vb_ + (2 * 16 + lc) * 64 + vRd);        \
    short8 vb3 = *(const short8*)(vb_ + (3 * 16 + lc) * 64 + vRd);        \
    const int kk_ = ksb + (W) * 32;                                       \
    floatx4 fa, fb;                                                       \
    fa[0] = bf2f(pw##W[0] & 0xffffu) * inv;                               \
    fa[1] = bf2f(pw##W[0] >> 16) * inv;                                   \
    fa[2] = bf2f(pw##W[1] & 0xffffu) * inv;                               \
    fa[3] = bf2f(pw##W[1] >> 16) * inv;                                   \
    fb[0] = bf2f(pw##W[2] & 0xffffu) * inv;                               \
    fb[1] = bf2f(pw##W[2] >> 16) * inv;                                   \
    fb[2] = bf2f(pw##W[3] & 0xffffu) * inv;                               \
    fb[3] = bf2f(pw##W[3] >> 16) * inv;                                   \
    __builtin_nontemporal_store(fa, (floatx4*)(arow + kk_));              \
    __builtin_nontemporal_store(fb, (floatx4*)(arow + kk_ + 4));          \
    short8 pa = __builtin_bit_cast(short8, pw##W);                        \
    o0 = MFMA(pa, vb0, o0, 0, 0, 0);                                      \
    o1 = MFMA(pa, vb1, o1, 0, 0, 0);                                      \
    o2 = MFMA(pa, vb2, o2, 0, 0, 0);                                      \
    o3 = MFMA(pa, vb3, o3, 0, 0, 0);                                      \
    WAITL;                                                                \
  }

  PVWIN(0, 0, 4)   VISSUE(2, 0)
  PVWIN(1, 1, 6)   VISSUE(3, 1)
  PVWIN(2, 0, 6)   VISSUE(4, 0)
  PVWIN(3, 1, 6)   VISSUE(5, 1)
  PVWIN(4, 0, 6)   VISSUE(6, 0)
  PVWIN(5, 1, 6)   VISSUE(7, 1)
  PVWIN(6, 0, 6)   VISSUE(8, 0)
  PVWIN(7, 1, 6)   VISSUE(9, 1)
  PVWIN(8, 0, 6)   VISSUE(10, 0)
  PVWIN(9, 1, 6)   VISSUE(11, 1)
  PVWIN(10, 0, 6)  VISSUE(12, 0)
  PVWIN(11, 1, 6)  VISSUE(13, 1)
  PVWIN(12, 0, 6)  VISSUE(14, 0)
  PVWIN(13, 1, 6)  VISSUE(15, 1)
  PVWIN(14, 0, 6)
  PVWIN(15, 1, 2)
#undef PVWIN
#undef VISSUE

  __syncthreads();  // drains everything; staging LDS now reusable
  float (*Ored)[16][72] = (float (*)[16][72])smem;  // 4*16*72*4 = 18432 B
#pragma unroll
  for (int r = 0; r < 4; ++r) {
    Ored[wave][lg4 + r][0 * 16 + lc] = o0[r];
    Ored[wave][lg4 + r][1 * 16 + lc] = o1[r];
    Ored[wave][lg4 + r][2 * 16 + lc] = o2[r];
    Ored[wave][lg4 + r][3 * 16 + lc] = o3[r];
  }
  __syncthreads();
  {
    const int q = tid >> 4;          // 0..15
    const int c4 = (tid & 15) * 4;   // 0..60
    floatx4 acc = {0.f, 0.f, 0.f, 0.f};
#pragma unroll
    for (int w = 0; w < 4; ++w) acc += *(const floatx4*)&Ored[w][q][c4];
    float tot = sums[0 * 16 + q] + sums[1 * 16 + q] + sums[2 * 16 + q] + sums[3 * 16 + q];
    const float invq = 1.f / tot;
    floatx4 res;
    res[0] = acc[0] * invq; res[1] = acc[1] * invq;
    res[2] = acc[2] * invq; res[3] = acc[3] * invq;
    __builtin_nontemporal_store(res, (floatx4*)(out + (bh * NS + (size_t)(q0 + q)) * ND + c4));
  }
}

extern "C" void kernel_launch(void* const* d_in, const int* in_sizes, int n_in,
                              void* d_out, int out_size, void* d_ws, size_t ws_size,
                              hipStream_t stream) {
  const float* Q = (const float*)d_in[0];
  const float* K = (const float*)d_in[1];
  const float* V = (const float*)d_in[2];
  const int* mask = (const int*)d_in[3];
  const float* bias = (const float*)d_in[4];

  float* out = (float*)d_out;
  float* attn = out + (size_t)NB * NH * NS * ND;  // outputs concatenated: (output, attn)

  unsigned short* kb = (unsigned short*)d_ws;                      // 16.8 MB
  unsigned short* vt = kb + (size_t)NB * NH * NS * ND;             // 16.8 MB
  unsigned* mb = (unsigned*)(vt + (size_t)NB * NH * NS * ND);      // 1 KB

  const int lds_bytes = 4 * 12288 + 4 * 16 * 4;  // 49408
  prep_k_kernel<<<(NB * NH * NS * ND) / (256 * 4), 256, 0, stream>>>(K, kb);
  prep_vt_kernel<<<NB * NH * (NS / 64), 256, 0, stream>>>(V, vt);
  prep_mask_kernel<<<1, 256, 0, stream>>>(mask, mb);
  attn_kernel<<<NB * NH * (NS / 16), 256, lds_bytes, stream>>>(Q, kb, vt, mb, bias, out, attn);
}